// Round 7
// baseline (85.397 us; speedup 1.0000x reference)
//
#include <hip/hip_runtime.h>

// x[2][4][128][128][128] f32, y[2][1][128][128][128] int32
constexpr int SPB = 1 << 21;
constexpr float EPSV = 1e-6f;

// Static scratch: packed per-voxel mask, 4 MB.
// mask[v] = (center_class << 4) | OR_{3x3x3 clipped}(1 << y[v+d])
__device__ unsigned char g_mask[2 * SPB];

// ===========================================================================
// K0: build packed 27-neighborhood presence mask + center class (proven R5)
// ===========================================================================
constexpr int K0_ZSEG = 4;
constexpr int K0_NBLK = (2 * (128 / K0_ZSEG) * 128) / 4;  // 2048

struct MEnt { int pk, cx, cy; };

__device__ __forceinline__ MEnt k0_load(const int* __restrict__ yb, int s,
                                        int rbase0, bool ym1, bool yp1) {
    MEnt e;
    const int rb = (s << 14) | rbase0;
    int2 vc = *(const int2*)(yb + rb);
    int nib0 = 1 << vc.x, nib1 = 1 << vc.y;
    if (ym1) { int2 vm = *(const int2*)(yb + rb - 128); nib0 |= 1 << vm.x; nib1 |= 1 << vm.y; }
    if (yp1) { int2 vp = *(const int2*)(yb + rb + 128); nib0 |= 1 << vp.x; nib1 |= 1 << vp.y; }
    e.pk = nib0 | (nib1 << 8);
    e.cx = vc.x; e.cy = vc.y;
    return e;
}

__global__ __launch_bounds__(256) void mask_build(const int* __restrict__ y32) {
    const int wid = (blockIdx.x << 2) | (threadIdx.x >> 6);
    const int lane = threadIdx.x & 63;
    const int yy = wid & 127;
    const int zs = (wid >> 7) & 31;
    const int b = (wid >> 12) & 1;
    const int x0 = lane << 1;
    const int z0 = zs * K0_ZSEG;
    const bool ym1 = yy > 0, yp1 = yy < 127;
    const int rbase0 = (yy << 7) | x0;

    const int* __restrict__ yb = y32 + ((long)b << 21);
    unsigned char* __restrict__ mb = g_mask + ((long)b << 21);

    MEnt e0, e1;
    if (z0 > 0) e0 = k0_load(yb, z0 - 1, rbase0, ym1, yp1);
    else { e0.pk = 0; e0.cx = 0; e0.cy = 0; }
    e1 = k0_load(yb, z0, rbase0, ym1, yp1);

#pragma unroll
    for (int dz = 0; dz < K0_ZSEG; ++dz) {
        const int z = z0 + dz;
        MEnt e2;
        if (z + 1 < 128) e2 = k0_load(yb, z + 1, rbase0, ym1, yp1);
        else { e2.pk = 0; e2.cx = 0; e2.cy = 0; }

        const int zor = e0.pk | e1.pk | e2.pk;
        int orL = __shfl_up(zor, 1);
        if (lane == 0) orL = 0;
        int orR = __shfl_down(zor, 1);
        if (lane == 63) orR = 0;
        const int full0 = (zor | (zor >> 8) | (orL >> 8)) & 15;
        const int full1 = (zor | (zor >> 8) | orR) & 15;

        const unsigned short st =
            (unsigned short)((full0 | (e1.cx << 4)) | ((full1 | (e1.cy << 4)) << 8));
        *(unsigned short*)(mb + ((z << 14) | rbase0)) = st;

        e0 = e1; e1 = e2;
    }
}

// ===========================================================================
// K1: main pass — Y-MARCHING. Wave = (plane, 2 output slices, 8-row y-chunk).
// 4 sequential slice-streams (z-1..z+2), 3-row rings of (1-x) in registers.
// All load streams advance 512 B/step -> page-dense, pipelineable.
// ===========================================================================
constexpr int NBLK = 2048;  // 8 planes * 16 z-groups * 16 y-chunks

__global__ __launch_bounds__(256, 6) void lah_main(const float* __restrict__ x,
                                                   float* __restrict__ acc) {
    const int bid = blockIdx.x;
    const int plane = bid & 7;              // -> XCD (round-robin dispatch)
    const int b = plane >> 2, cls = plane & 3;
    const int r = bid >> 3;                 // 0..255
    const int zg = r & 15;                  // z-group: 4 slabs of 2 slices
    const int yc = r >> 4;                  // 0..15, y-chunk of 8 rows
    const int w = threadIdx.x >> 6;         // wave in block -> slab
    const int lane = threadIdx.x & 63;
    const int z0 = (zg * 4 + w) * 2;        // first output slice (0..126, even)
    const int y0 = yc * 8;
    const int lx2 = lane << 1;              // x positions lx2, lx2+1

    const float* __restrict__ xp = x + ((long)plane << 21);
    const unsigned char* __restrict__ mb = g_mask + ((long)b << 21);

    // stream s covers slice z0-1+s, s=0..3
    const bool vs0 = (z0 > 0);
    const bool vs3 = (z0 + 2 < 128);

    // load (1-x) pair for stream s at row y; padded regions -> 1
    auto loadrow = [&](int s, int y) -> float2 {
        const bool ok = (s == 0 ? vs0 : (s == 3 ? vs3 : true)) &&
                        (y >= 0) && (y <= 127);
        if (!ok) return make_float2(1.f, 1.f);
        const float2 xv = *(const float2*)(xp + (((z0 - 1 + s) << 14) | (y << 7) | lx2));
        return make_float2(1.f - xv.x, 1.f - xv.y);
    };
    auto loadmask = [&](int zo, int y) -> unsigned {
        return (unsigned)*(const unsigned short*)(mb + (((z0 + zo) << 14) | (y << 7) | lx2));
    };

    float fp = 0.f, fn = 0.f, sx = 0.f, sy = 0.f;

    // rings: om[s][0..2] = (1-x) rows y-1, y, y+1
    float2 om[4][3];
#pragma unroll
    for (int s = 0; s < 4; ++s) {
        om[s][0] = loadrow(s, y0 - 1);
        om[s][1] = loadrow(s, y0);
        om[s][2] = loadrow(s, y0 + 1);
    }
    unsigned mk0 = loadmask(0, y0);
    unsigned mk1 = loadmask(1, y0);

#pragma unroll
    for (int dy = 0; dy < 8; ++dy) {
        const int y = y0 + dy;

        // --- prefetch row y+2 (all 4 streams) and masks for row y+1 ---
        float2 nx[4];
#pragma unroll
        for (int s = 0; s < 4; ++s)
            nx[s] = (dy < 7) ? loadrow(s, y + 2) : make_float2(1.f, 1.f);
        const unsigned nm0 = (dy < 7) ? loadmask(0, y + 1) : 0u;
        const unsigned nm1 = (dy < 7) ? loadmask(1, y + 1) : 0u;

        // --- y-products per stream ---
        float yPx[4], yPy[4];
#pragma unroll
        for (int s = 0; s < 4; ++s) {
            yPx[s] = om[s][0].x * om[s][1].x * om[s][2].x;
            yPy[s] = om[s][0].y * om[s][1].y * om[s][2].y;
        }

        // --- per output slice: z-product, x-shuffles, accumulate ---
#pragma unroll
        for (int zo = 0; zo < 2; ++zo) {
            const float zp0 = yPx[zo] * yPx[zo + 1] * yPx[zo + 2];
            const float zp1 = yPy[zo] * yPy[zo + 1] * yPy[zo + 2];
            float zl = __shfl_up(zp1, 1);
            if (lane == 0) zl = 1.f;
            float zr = __shfl_down(zp0, 1);
            if (lane == 63) zr = 1.f;
            const float t = zp0 * zp1;
            const float P0 = zl * t, P1 = t * zr;

            const float xv0 = 1.f - om[zo + 1][1].x;
            const float xv1 = 1.f - om[zo + 1][1].y;
            const unsigned m = zo ? mk1 : mk0;
            const int m0 = m & 0xFF, m1 = (m >> 8) & 0xFF;
            const bool pr0 = (m0 >> cls) & 1, pr1 = (m1 >> cls) & 1;
            const bool eq0 = (m0 >> 4) == cls, eq1 = (m1 >> 4) == cls;

            sx += xv0 + xv1;
            fp += eq0 ? 0.f : xv0 * (pr0 ? 1.f : 2.f);
            fp += eq1 ? 0.f : xv1 * (pr1 ? 1.f : 2.f);
            fn += eq0 ? (1.f - xv0) * (1.f + P0) : 0.f;
            fn += eq1 ? (1.f - xv1) * (1.f + P1) : 0.f;
            sy += (eq0 ? 1.f : 0.f) + (eq1 ? 1.f : 0.f);
        }

        // --- rotate rings ---
#pragma unroll
        for (int s = 0; s < 4; ++s) {
            om[s][0] = om[s][1];
            om[s][1] = om[s][2];
            om[s][2] = nx[s];
        }
        mk0 = nm0;
        mk1 = nm1;
    }

    // ---- reduce 4 scalars: wave shuffle -> block LDS -> global atomics ----
    float rr[4] = {fp, fn, sx, sy};
    __shared__ float s[4];
#pragma unroll
    for (int i = 0; i < 4; ++i) {
        float vv = rr[i];
#pragma unroll
        for (int off = 32; off >= 1; off >>= 1) vv += __shfl_down(vv, off);
        rr[i] = vv;
    }
    if (threadIdx.x < 4) s[threadIdx.x] = 0.f;
    __syncthreads();
    if (lane == 0) {
#pragma unroll
        for (int i = 0; i < 4; ++i) atomicAdd(&s[i], rr[i]);
    }
    __syncthreads();
    if (threadIdx.x < 4)
        atomicAdd(&acc[b * 16 + threadIdx.x * 4 + cls], s[threadIdx.x]);
}

// ===========================================================================
// K2: finalize scalar loss
// ===========================================================================
__global__ void lah_finalize(const float* __restrict__ acc, float* __restrict__ out) {
    float loss = 0.f;
#pragma unroll
    for (int b = 0; b < 2; ++b) {
#pragma unroll
        for (int c = 1; c < 4; ++c) {
            const float fp = acc[b * 16 + 0 + c];
            const float fn = acc[b * 16 + 4 + c];
            const float sxv = acc[b * 16 + 8 + c];
            const float syv = acc[b * 16 + 12 + c];
            loss += fmaxf(fp / (sxv + EPSV), fn / (syv + EPSV));
        }
    }
    out[0] = loss / 6.f;
}

extern "C" void kernel_launch(void* const* d_in, const int* in_sizes, int n_in,
                              void* d_out, int out_size, void* d_ws, size_t ws_size,
                              hipStream_t stream) {
    const float* x = (const float*)d_in[0];
    const int* y32 = (const int*)d_in[1];
    float* out = (float*)d_out;
    float* acc = (float*)d_ws;  // 32 floats

    hipMemsetAsync(d_ws, 0, 32 * sizeof(float), stream);
    mask_build<<<K0_NBLK, 256, 0, stream>>>(y32);
    lah_main<<<NBLK, 256, 0, stream>>>(x, acc);
    lah_finalize<<<1, 1, 0, stream>>>(acc, out);
}

// Round 8
// 41.725 us; speedup vs baseline: 2.0466x; 2.0466x over previous
//
#include <hip/hip_runtime.h>

// x[2][4][128][128][128] f32, y[2][1][128][128][128] int32
constexpr int SPB = 1 << 21;
constexpr float EPSV = 1e-6f;

// Static scratch: packed per-voxel mask, 4 MB.
// mask[v] = (center_class << 4) | OR_{3x3x3 clipped}(1 << y[v+d])
__device__ unsigned char g_mask[2 * SPB];

// ===========================================================================
// K0: build packed 27-neighborhood presence mask + center class (proven R5)
// ===========================================================================
constexpr int K0_ZSEG = 4;
constexpr int K0_NBLK = (2 * (128 / K0_ZSEG) * 128) / 4;  // 2048

struct MEnt { int pk, cx, cy; };

__device__ __forceinline__ MEnt k0_load(const int* __restrict__ yb, int s,
                                        int rbase0, bool ym1, bool yp1) {
    MEnt e;
    const int rb = (s << 14) | rbase0;
    int2 vc = *(const int2*)(yb + rb);
    int nib0 = 1 << vc.x, nib1 = 1 << vc.y;
    if (ym1) { int2 vm = *(const int2*)(yb + rb - 128); nib0 |= 1 << vm.x; nib1 |= 1 << vm.y; }
    if (yp1) { int2 vp = *(const int2*)(yb + rb + 128); nib0 |= 1 << vp.x; nib1 |= 1 << vp.y; }
    e.pk = nib0 | (nib1 << 8);
    e.cx = vc.x; e.cy = vc.y;
    return e;
}

__global__ __launch_bounds__(256) void mask_build(const int* __restrict__ y32) {
    const int wid = (blockIdx.x << 2) | (threadIdx.x >> 6);
    const int lane = threadIdx.x & 63;
    const int yy = wid & 127;
    const int zs = (wid >> 7) & 31;
    const int b = (wid >> 12) & 1;
    const int x0 = lane << 1;
    const int z0 = zs * K0_ZSEG;
    const bool ym1 = yy > 0, yp1 = yy < 127;
    const int rbase0 = (yy << 7) | x0;

    const int* __restrict__ yb = y32 + ((long)b << 21);
    unsigned char* __restrict__ mb = g_mask + ((long)b << 21);

    MEnt e0, e1;
    if (z0 > 0) e0 = k0_load(yb, z0 - 1, rbase0, ym1, yp1);
    else { e0.pk = 0; e0.cx = 0; e0.cy = 0; }
    e1 = k0_load(yb, z0, rbase0, ym1, yp1);

#pragma unroll
    for (int dz = 0; dz < K0_ZSEG; ++dz) {
        const int z = z0 + dz;
        MEnt e2;
        if (z + 1 < 128) e2 = k0_load(yb, z + 1, rbase0, ym1, yp1);
        else { e2.pk = 0; e2.cx = 0; e2.cy = 0; }

        const int zor = e0.pk | e1.pk | e2.pk;
        int orL = __shfl_up(zor, 1);
        if (lane == 0) orL = 0;
        int orR = __shfl_down(zor, 1);
        if (lane == 63) orR = 0;
        const int full0 = (zor | (zor >> 8) | (orL >> 8)) & 15;
        const int full1 = (zor | (zor >> 8) | orR) & 15;

        const unsigned short st =
            (unsigned short)((full0 | (e1.cx << 4)) | ((full1 | (e1.cy << 4)) << 8));
        *(unsigned short*)(mb + ((z << 14) | rbase0)) = st;

        e0 = e1; e1 = e2;
    }
}

// ===========================================================================
// K1: LDS-staged block stencil. Block = (plane, 8 rows, all x, 16 z-slices).
// Ring-of-3 raw slices [10][128] + ring-of-3 y-product slices [8][128] in LDS.
// One contiguous 5KB float4 stage per z-step, double-buffered via registers.
// ===========================================================================
constexpr int NBLK = 1024;  // 8 planes * 16 y-chunks * 8 z-chunks

__global__ __launch_bounds__(256) void lah_main(const float* __restrict__ x,
                                                float* __restrict__ acc) {
    __shared__ float raw[3][10][128];   // raw x, rows r0-1 .. r0+8
    __shared__ float yp[3][8][128];     // 3-row y-products of (1-x), center rows
    __shared__ float sred[4];

    const int bid = blockIdx.x;
    const int plane = bid & 7;            // -> XCD (round-robin dispatch)
    const int b = plane >> 2, cls = plane & 3;
    const int inner = bid >> 3;           // 0..127
    const int yc = inner & 15;
    const int zq = inner >> 4;            // 0..7
    const int r0 = yc * 8;
    const int z0 = zq * 16;
    const int t = threadIdx.x;
    const int rr = t >> 5;                // 0..7 (center-row index)
    const int xc = (t & 31) << 2;         // 0,4,...,124
    const int lane = t & 63;

    const float* __restrict__ xp = x + ((long)plane << 21);
    const unsigned char* __restrict__ mb = g_mask + ((long)b << 21);
    const int mrow = (r0 + rr) << 7;

    auto slot = [](int k) -> int { return (k + 129) % 3; };

    // load float4 of global slice k, local row i (0..9); OOB -> zeros
    auto gload = [&](int k, int i, int c4) -> float4 {
        const int gr = r0 - 1 + i;
        if ((unsigned)k > 127u || (unsigned)gr > 127u)
            return make_float4(0.f, 0.f, 0.f, 0.f);
        return *(const float4*)(xp + ((k << 14) | (gr << 7) | c4));
    };

    auto stage_direct = [&](int k) {
        const int s = slot(k);
        float4 v = gload(k, rr, xc);
        *(float4*)&raw[s][rr][xc] = v;
        if (t < 64) {
            const int i = 8 + (t >> 5);
            float4 w = gload(k, i, xc);
            *(float4*)&raw[s][i][xc] = w;
        }
    };

    auto do_yprod = [&](int k) {
        const int s = slot(k);
        const float4 a = *(const float4*)&raw[s][rr][xc];
        const float4 bq = *(const float4*)&raw[s][rr + 1][xc];
        const float4 c = *(const float4*)&raw[s][rr + 2][xc];
        float4 o;
        o.x = (1.f - a.x) * (1.f - bq.x) * (1.f - c.x);
        o.y = (1.f - a.y) * (1.f - bq.y) * (1.f - c.y);
        o.z = (1.f - a.z) * (1.f - bq.z) * (1.f - c.z);
        o.w = (1.f - a.w) * (1.f - bq.w) * (1.f - c.w);
        *(float4*)&yp[s][rr][xc] = o;
    };

    // ---- prologue: stage slices z0-1, z0, z0+1; y-products for z0-1, z0 ----
    stage_direct(z0 - 1);
    stage_direct(z0);
    stage_direct(z0 + 1);
    __syncthreads();
    do_yprod(z0 - 1);
    do_yprod(z0);
    unsigned mcur = *(const unsigned*)(mb + ((z0 << 14) | mrow | xc));

    float fp = 0.f, fn = 0.f, sx = 0.f, sy = 0.f;

    for (int dz = 0; dz < 16; ++dz) {
        const int z = z0 + dz;

        // Phase 1: issue global prefetch of slice z+2 into regs; mask z+1
        float4 gA = gload(z + 2, rr, xc);
        float4 gB = make_float4(0.f, 0.f, 0.f, 0.f);
        if (t < 64) gB = gload(z + 2, 8 + (t >> 5), xc);
        unsigned mnext = 0;
        if (dz < 15)
            mnext = *(const unsigned*)(mb + (((z + 1) << 14) | mrow | xc));

        // Phase 2: y-products of slice z+1 (raw staged last iteration)
        do_yprod(z + 1);
        __syncthreads();  // B1: yp[z+1] visible

        // Phase 3: compute voxels of slice z
        {
            const int sA = slot(z - 1), sB = slot(z), sC = slot(z + 1);
            const float4 a = *(const float4*)&yp[sA][rr][xc];
            const float4 bq = *(const float4*)&yp[sB][rr][xc];
            const float4 c = *(const float4*)&yp[sC][rr][xc];
            const float zp0 = a.x * bq.x * c.x;
            const float zp1 = a.y * bq.y * c.y;
            const float zp2 = a.z * bq.z * c.z;
            const float zp3 = a.w * bq.w * c.w;
            float zl = __shfl_up(zp3, 1);
            if ((t & 31) == 0) zl = 1.f;
            float zr = __shfl_down(zp0, 1);
            if ((t & 31) == 31) zr = 1.f;
            const float t01 = zp0 * zp1, t12 = zp1 * zp2, t23 = zp2 * zp3;
            const float P[4] = {zl * t01, t01 * zp2, t12 * zp3, t23 * zr};

            const float4 xv4 = *(const float4*)&raw[sB][rr + 1][xc];
            const float xa[4] = {xv4.x, xv4.y, xv4.z, xv4.w};
#pragma unroll
            for (int j = 0; j < 4; ++j) {
                const int m = (mcur >> (j * 8)) & 0xFF;
                const bool pres = (m >> cls) & 1;
                const bool eq = (m >> 4) == cls;
                const float xv = xa[j];
                sx += xv;
                fp += eq ? 0.f : xv * (pres ? 1.f : 2.f);
                fn += eq ? (1.f - xv) * (1.f + P[j]) : 0.f;
                sy += eq ? 1.f : 0.f;
            }
        }

        // Phase 4: write prefetched slice z+2 into raw ring
        {
            const int s = slot(z + 2);
            *(float4*)&raw[s][rr][xc] = gA;
            if (t < 64) *(float4*)&raw[s][8 + (t >> 5)][xc] = gB;
        }
        __syncthreads();  // B2: raw[z+2] visible for next iteration
        mcur = mnext;
    }

    // ---- reduce 4 scalars: wave shuffle -> block LDS -> global atomics ----
    float rr4[4] = {fp, fn, sx, sy};
#pragma unroll
    for (int i = 0; i < 4; ++i) {
        float vv = rr4[i];
#pragma unroll
        for (int off = 32; off >= 1; off >>= 1) vv += __shfl_down(vv, off);
        rr4[i] = vv;
    }
    if (t < 4) sred[t] = 0.f;
    __syncthreads();
    if (lane == 0) {
#pragma unroll
        for (int i = 0; i < 4; ++i) atomicAdd(&sred[i], rr4[i]);
    }
    __syncthreads();
    if (t < 4)
        atomicAdd(&acc[b * 16 + t * 4 + cls], sred[t]);
}

// ===========================================================================
// K2: finalize scalar loss
// ===========================================================================
__global__ void lah_finalize(const float* __restrict__ acc, float* __restrict__ out) {
    float loss = 0.f;
#pragma unroll
    for (int b = 0; b < 2; ++b) {
#pragma unroll
        for (int c = 1; c < 4; ++c) {
            const float fp = acc[b * 16 + 0 + c];
            const float fn = acc[b * 16 + 4 + c];
            const float sxv = acc[b * 16 + 8 + c];
            const float syv = acc[b * 16 + 12 + c];
            loss += fmaxf(fp / (sxv + EPSV), fn / (syv + EPSV));
        }
    }
    out[0] = loss / 6.f;
}

extern "C" void kernel_launch(void* const* d_in, const int* in_sizes, int n_in,
                              void* d_out, int out_size, void* d_ws, size_t ws_size,
                              hipStream_t stream) {
    const float* x = (const float*)d_in[0];
    const int* y32 = (const int*)d_in[1];
    float* out = (float*)d_out;
    float* acc = (float*)d_ws;  // 32 floats

    hipMemsetAsync(d_ws, 0, 32 * sizeof(float), stream);
    mask_build<<<K0_NBLK, 256, 0, stream>>>(y32);
    lah_main<<<NBLK, 256, 0, stream>>>(x, acc);
    lah_finalize<<<1, 1, 0, stream>>>(acc, out);
}